// Round 7
// baseline (5195.776 us; speedup 1.0000x reference)
//
#include <hip/hip_runtime.h>

// SpMM: out[r,:] = in_norm[r] * sum_{e: row[e]==r} (values[e]*out_norm[col[e]]) * x[col[e],:]
// v3 fast path: bin edges by row>>6 (L2-friendly scatter), then fused per-bin
// gather with LDS f32 accumulation (64 rows x 256 feats = 64KB) + bf16 x.
// Fallbacks: bucket path (R6), exact CSR, atomic scatter.

typedef float f32x4 __attribute__((ext_vector_type(4)));
typedef unsigned int u32x4 __attribute__((ext_vector_type(4)));
typedef unsigned long long u64;

#define BUCKET_LOG2 6
#define BUCKET_CAP  64
#define OVF_CAP     8192
#define BIN_LOG2    6          // 64 rows per bin
#define MAX_BINS    4096

// ---------------- bf16 helpers ----------------
__device__ inline unsigned pack_bf16x2(float lo, float hi) {
    unsigned ua = __float_as_uint(lo);
    unsigned ub = __float_as_uint(hi);
    ua = (ua + 0x7FFFu + ((ua >> 16) & 1u)) >> 16;        // RNE
    ub = (ub + 0x7FFFu + ((ub >> 16) & 1u)) >> 16;
    return ua | (ub << 16);
}
__device__ inline float bf_lo(unsigned u) { return __uint_as_float(u << 16); }
__device__ inline float bf_hi(unsigned u) { return __uint_as_float(u & 0xFFFF0000u); }

// ---------------- fallback (atomic scatter) ----------------
__global__ void zero_out_kernel(float4* out, int n4) {
    int i = blockIdx.x * blockDim.x + threadIdx.x;
    int stride = gridDim.x * blockDim.x;
    for (; i < n4; i += stride) out[i] = make_float4(0.f, 0.f, 0.f, 0.f);
}

__global__ __launch_bounds__(256) void edge_scatter_kernel(
    const float* __restrict__ x, const int* __restrict__ row,
    const int* __restrict__ col, const float* __restrict__ values,
    const float* __restrict__ out_norm, const float* __restrict__ in_norm,
    float* __restrict__ out, int E, int D)
{
    int wave_in_block = threadIdx.x >> 6;
    int lane = threadIdx.x & 63;
    int e = blockIdx.x * 4 + wave_in_block;
    if (e >= E) return;
    int r = row[e], c = col[e];
    float s = values[e] * out_norm[c] * in_norm[r];
    const float4* xs = reinterpret_cast<const float4*>(x + (size_t)c * D);
    float4 v = xs[lane];
    float* o = out + (size_t)r * D + lane * 4;
    atomicAdd(o + 0, v.x * s);
    atomicAdd(o + 1, v.y * s);
    atomicAdd(o + 2, v.z * s);
    atomicAdd(o + 3, v.w * s);
}

// ---------------- x -> bf16 compression (NT loads: x read-once) -------------
__global__ __launch_bounds__(256) void convert_bf16_kernel(
    const u32x4* __restrict__ x, u32x4* __restrict__ xh, int n8)
{
    int i = blockIdx.x * blockDim.x + threadIdx.x;
    int stride = gridDim.x * blockDim.x;
    for (; i < n8; i += stride) {
        u32x4 a = __builtin_nontemporal_load(&x[2 * i]);
        u32x4 b = __builtin_nontemporal_load(&x[2 * i + 1]);
        u32x4 o;
        o.x = pack_bf16x2(__uint_as_float(a.x), __uint_as_float(a.y));
        o.y = pack_bf16x2(__uint_as_float(a.z), __uint_as_float(a.w));
        o.z = pack_bf16x2(__uint_as_float(b.x), __uint_as_float(b.y));
        o.w = pack_bf16x2(__uint_as_float(b.z), __uint_as_float(b.w));
        xh[i] = o;
    }
}

// ================= v3: bin-based fused path =================

// per-block LDS histogram of bins
__global__ __launch_bounds__(256) void hist_bins_kernel(
    const int* __restrict__ row, int* __restrict__ bin_cnt, int E, int nbins)
{
    __shared__ int h[MAX_BINS];
    for (int i = threadIdx.x; i < nbins; i += 256) h[i] = 0;
    __syncthreads();
    int i = blockIdx.x * blockDim.x + threadIdx.x;
    int stride = gridDim.x * blockDim.x;
    for (; i < E; i += stride) {
        int r = __builtin_nontemporal_load(&row[i]);
        atomicAdd(&h[r >> BIN_LOG2], 1);
    }
    __syncthreads();
    for (int b = threadIdx.x; b < nbins; b += 256) {
        int v = h[b];
        if (v) atomicAdd(&bin_cnt[b], v);
    }
}

// single-wave rolling exclusive scan of bins -> bin_off and bin_cur
__global__ void scan_bins_kernel(const int* __restrict__ bin_cnt,
                                 int* __restrict__ bin_off,
                                 int* __restrict__ bin_cur, int nbins)
{
    int lane = threadIdx.x & 63;
    int run = 0;
    for (int base = 0; base < nbins; base += 64) {
        int i = base + lane;
        int v = (i < nbins) ? bin_cnt[i] : 0;
        int s = v;
        #pragma unroll
        for (int d = 1; d < 64; d <<= 1) {
            int t = __shfl_up(s, d);
            if (lane >= d) s += t;
        }
        int excl = run + s - v;
        if (i < nbins) { bin_off[i] = excl; bin_cur[i] = excl; }
        run += __shfl(s, 63);
    }
    if (lane == 0) bin_off[nbins] = run;
}

// scatter (pc, v) into bin regions; hot tail = 1 line/bin -> L2-coalesced
__global__ __launch_bounds__(256) void binfill_kernel(
    const int* __restrict__ row, const int* __restrict__ col,
    const float* __restrict__ values, const float* __restrict__ out_norm,
    int* __restrict__ bin_cur, u64* __restrict__ pairs, int E)
{
    int i = blockIdx.x * blockDim.x + threadIdx.x;
    int stride = gridDim.x * blockDim.x;
    for (; i < E; i += stride) {
        int r = __builtin_nontemporal_load(&row[i]);
        int c = __builtin_nontemporal_load(&col[i]);
        float vv = __builtin_nontemporal_load(&values[i]);
        float v = vv * out_norm[c];
        unsigned pc = (unsigned)c | ((unsigned)(r & (BUCKET_CAP - 1)) << 18);
        u64 packed = (u64)pc | ((u64)__float_as_uint(v) << 32);
        int pos = atomicAdd(&bin_cur[r >> BIN_LOG2], 1);
        pairs[pos] = packed;                 // normal store: keep tail line hot
    }
}

// fused per-bin gather: LDS f32 accumulate + coalesced writeout. D==256 only.
// LDS swizzle: feat (4l+j) of row rl lives at word rl*256 + 64j + l
// -> both the atomic phase and the read phase are bank-conflict-free.
__global__ __launch_bounds__(512) void fused_bin_gather_kernel(
    const unsigned short* __restrict__ xh, const u64* __restrict__ pairs,
    const int* __restrict__ bin_off, const float* __restrict__ in_norm,
    float* __restrict__ out, int N)
{
    __shared__ float acc[64 * 256];          // 64 KB
    const int DU2 = 64;                      // uint2 (4 bf16) per row
    int tid = threadIdx.x;
    int lane = tid & 63;
    int w = tid >> 6;                        // wave 0..7
    int bin = blockIdx.x;

    #pragma unroll
    for (int i = 0; i < 32; ++i) acc[tid + 512 * i] = 0.f;
    __syncthreads();

    int beg = bin_off[bin], end = bin_off[bin + 1];
    const uint2* xr = reinterpret_cast<const uint2*>(xh);

    for (int base = beg + (w << 6); base < end; base += 512) {
        int j = base + lane;
        u64 pr = (j < end) ? __builtin_nontemporal_load(&pairs[j]) : 0ull;
        unsigned prlo = (unsigned)(pr & 0xFFFFFFFFu);
        unsigned prhi = (unsigned)(pr >> 32);
        int m = min(64, end - base);
        int kk = 0;
        for (; kk + 8 <= m; kk += 8) {
            uint2 q[8]; float vv[8]; int rl[8];
            #pragma unroll
            for (int t = 0; t < 8; ++t) {
                unsigned pc = (unsigned)__builtin_amdgcn_readlane((int)prlo, kk + t);
                unsigned vb = (unsigned)__builtin_amdgcn_readlane((int)prhi, kk + t);
                vv[t] = __uint_as_float(vb);
                rl[t] = (int)(pc >> 18);
                q[t] = xr[(size_t)(pc & 0x3FFFFu) * DU2 + lane];  // 8 indep loads
            }
            #pragma unroll
            for (int t = 0; t < 8; ++t) {
                float* ar = &acc[rl[t] * 256];
                atomicAdd(&ar[lane      ], vv[t] * bf_lo(q[t].x));
                atomicAdd(&ar[lane +  64], vv[t] * bf_hi(q[t].x));
                atomicAdd(&ar[lane + 128], vv[t] * bf_lo(q[t].y));
                atomicAdd(&ar[lane + 192], vv[t] * bf_hi(q[t].y));
            }
        }
        for (; kk < m; ++kk) {
            unsigned pc = (unsigned)__builtin_amdgcn_readlane((int)prlo, kk);
            unsigned vb = (unsigned)__builtin_amdgcn_readlane((int)prhi, kk);
            float v = __uint_as_float(vb);
            int rl = (int)(pc >> 18);
            uint2 q = xr[(size_t)(pc & 0x3FFFFu) * DU2 + lane];
            float* ar = &acc[rl * 256];
            atomicAdd(&ar[lane      ], v * bf_lo(q.x));
            atomicAdd(&ar[lane +  64], v * bf_hi(q.x));
            atomicAdd(&ar[lane + 128], v * bf_lo(q.y));
            atomicAdd(&ar[lane + 192], v * bf_hi(q.y));
        }
    }
    __syncthreads();

    // writeout: wave w handles rows {w, w+8, ..., w+56}
    int r0 = bin << BIN_LOG2;
    #pragma unroll
    for (int i = 0; i < 8; ++i) {
        int rl = w + (i << 3);
        int r = r0 + rl;
        if (r < N) {
            float sc = in_norm[r];
            const float* ar = &acc[rl * 256];
            float a0 = ar[lane], a1 = ar[lane + 64];
            float a2 = ar[lane + 128], a3 = ar[lane + 192];
            f32x4 o;
            o.x = a0 * sc; o.y = a1 * sc; o.z = a2 * sc; o.w = a3 * sc;
            __builtin_nontemporal_store(
                o, reinterpret_cast<f32x4*>(out + (size_t)r * 256 + 4 * lane));
        }
    }
}

// ================= R6 bucket path (fallback #1, D==256) =================
__global__ __launch_bounds__(256) void fill_bucket_kernel(
    const int* __restrict__ row, const int* __restrict__ col,
    const float* __restrict__ values, const float* __restrict__ out_norm,
    int* __restrict__ cursor, u64* __restrict__ pairs,
    int* __restrict__ ovf_cnt, int* __restrict__ ovf_r, u64* __restrict__ ovf_cv,
    int E)
{
    int i = blockIdx.x * blockDim.x + threadIdx.x;
    int stride = gridDim.x * blockDim.x;
    for (; i < E; i += stride) {
        int r = __builtin_nontemporal_load(&row[i]);
        int c = __builtin_nontemporal_load(&col[i]);
        float vv = __builtin_nontemporal_load(&values[i]);
        float v = vv * out_norm[c];
        u64 packed = (u64)(unsigned)c | ((u64)__float_as_uint(v) << 32);
        int n = atomicAdd(&cursor[r], 1);
        if (n < BUCKET_CAP) {
            __builtin_nontemporal_store(packed, &pairs[((size_t)r << BUCKET_LOG2) + n]);
        } else {
            int o = atomicAdd(ovf_cnt, 1);
            if (o < OVF_CAP) { ovf_r[o] = r; ovf_cv[o] = packed; }
        }
    }
}

__global__ __launch_bounds__(256) void gather_bucket_kernel(
    const unsigned short* __restrict__ xh, const u64* __restrict__ pairs,
    const int* __restrict__ cursor, const float* __restrict__ in_norm,
    float* __restrict__ out, int N)
{
    const int DU2 = 64;
    int wid = threadIdx.x >> 6;
    int lane = threadIdx.x & 63;
    int r = blockIdx.x * 4 + wid;
    if (r >= N) return;

    int m = cursor[r];
    if (m > BUCKET_CAP) m = BUCKET_CAP;

    u64 pr = (lane < m)
        ? __builtin_nontemporal_load(&pairs[((size_t)r << BUCKET_LOG2) + lane])
        : 0ull;
    unsigned prlo = (unsigned)(pr & 0xFFFFFFFFu);
    unsigned prhi = (unsigned)(pr >> 32);

    float4 acc = make_float4(0.f, 0.f, 0.f, 0.f);
    const uint2* xr = reinterpret_cast<const uint2*>(xh);

    int kk = 0;
    for (; kk + 8 <= m; kk += 8) {
        uint2 q[8]; float vv[8];
        #pragma unroll
        for (int t = 0; t < 8; ++t) {
            int c = __builtin_amdgcn_readlane((int)prlo, kk + t);
            unsigned vb = (unsigned)__builtin_amdgcn_readlane((int)prhi, kk + t);
            vv[t] = __uint_as_float(vb);
            q[t] = xr[(size_t)(unsigned)c * DU2 + lane];
        }
        #pragma unroll
        for (int t = 0; t < 8; ++t) {
            acc.x += vv[t] * bf_lo(q[t].x);
            acc.y += vv[t] * bf_hi(q[t].x);
            acc.z += vv[t] * bf_lo(q[t].y);
            acc.w += vv[t] * bf_hi(q[t].y);
        }
    }
    for (; kk < m; ++kk) {
        int c = __builtin_amdgcn_readlane((int)prlo, kk);
        unsigned vb = (unsigned)__builtin_amdgcn_readlane((int)prhi, kk);
        float v = __uint_as_float(vb);
        uint2 q = xr[(size_t)(unsigned)c * DU2 + lane];
        acc.x += v * bf_lo(q.x);
        acc.y += v * bf_hi(q.x);
        acc.z += v * bf_lo(q.y);
        acc.w += v * bf_hi(q.y);
    }

    float sc = in_norm[r];
    f32x4 o;
    o.x = acc.x * sc; o.y = acc.y * sc; o.z = acc.z * sc; o.w = acc.w * sc;
    f32x4* ob = reinterpret_cast<f32x4*>(out);
    __builtin_nontemporal_store(o, &ob[(size_t)r * DU2 + lane]);
}

__global__ __launch_bounds__(256) void fixup_kernel(
    const unsigned short* __restrict__ xh, const int* __restrict__ ovf_cnt,
    const int* __restrict__ ovf_r, const u64* __restrict__ ovf_cv,
    const float* __restrict__ in_norm, float* __restrict__ out)
{
    const int DU2 = 64;
    int total = *ovf_cnt;
    if (total > OVF_CAP) total = OVF_CAP;
    int wid = (blockIdx.x * blockDim.x + threadIdx.x) >> 6;
    int nw = (gridDim.x * blockDim.x) >> 6;
    int lane = threadIdx.x & 63;
    const uint2* xr = reinterpret_cast<const uint2*>(xh);
    for (int i = wid; i < total; i += nw) {
        int r = ovf_r[i];
        u64 p = ovf_cv[i];
        int c = (int)(unsigned)(p & 0xFFFFFFFFu);
        float v = __uint_as_float((unsigned)(p >> 32)) * in_norm[r];
        uint2 q = xr[(size_t)(unsigned)c * DU2 + lane];
        float* o = out + (size_t)r * 256 + lane * 4;
        atomicAdd(o + 0, v * bf_lo(q.x));
        atomicAdd(o + 1, v * bf_hi(q.x));
        atomicAdd(o + 2, v * bf_lo(q.y));
        atomicAdd(o + 3, v * bf_hi(q.y));
    }
}

// ================= exact CSR path (fallback #2, generic D) =================
__global__ __launch_bounds__(256) void hist_kernel(
    const int* __restrict__ row, int* __restrict__ counts, int E)
{
    int i = blockIdx.x * blockDim.x + threadIdx.x;
    int stride = gridDim.x * blockDim.x;
    for (; i < E; i += stride) atomicAdd(&counts[row[i]], 1);
}

__global__ __launch_bounds__(256) void block_sum_kernel(
    const int* __restrict__ counts, int* __restrict__ partials, int N)
{
    int base = blockIdx.x * 1024;
    int tid = threadIdx.x;
    int s = 0;
    int idx = base + tid * 4;
    #pragma unroll
    for (int k = 0; k < 4; ++k) { int i = idx + k; if (i < N) s += counts[i]; }
    #pragma unroll
    for (int d = 32; d >= 1; d >>= 1) s += __shfl_down(s, d);
    __shared__ int wsum[4];
    int lane = tid & 63, wid = tid >> 6;
    if (lane == 0) wsum[wid] = s;
    __syncthreads();
    if (tid == 0) partials[blockIdx.x] = wsum[0] + wsum[1] + wsum[2] + wsum[3];
}

__global__ void scan_partials_kernel(int* partials, int nb) {
    if (blockIdx.x == 0 && threadIdx.x == 0) {
        int sum = 0;
        for (int b = 0; b < nb; ++b) { int t = partials[b]; partials[b] = sum; sum += t; }
    }
}

__global__ __launch_bounds__(256) void scan_block_kernel(
    const int* __restrict__ counts, const int* __restrict__ partials,
    int* __restrict__ row_ptr, int N)
{
    int b = blockIdx.x;
    int base = b * 1024;
    int tid = threadIdx.x;
    int lane = tid & 63, wid = tid >> 6;
    int idx = base + tid * 4;

    int c0 = (idx + 0 < N) ? counts[idx + 0] : 0;
    int c1 = (idx + 1 < N) ? counts[idx + 1] : 0;
    int c2 = (idx + 2 < N) ? counts[idx + 2] : 0;
    int c3 = (idx + 3 < N) ? counts[idx + 3] : 0;
    int i0 = c0, i1 = i0 + c1, i2 = i1 + c2, i3 = i2 + c3;

    int s = i3;
    #pragma unroll
    for (int d = 1; d < 64; d <<= 1) {
        int t = __shfl_up(s, d);
        if (lane >= d) s += t;
    }
    int excl = s - i3;

    __shared__ int wsum[4];
    if (lane == 63) wsum[wid] = s;
    __syncthreads();
    int woff = 0;
    for (int w = 0; w < wid; ++w) woff += wsum[w];

    int off = partials[b] + woff + excl;
    if (idx + 0 < N) row_ptr[idx + 1] = off + i0;
    if (idx + 1 < N) row_ptr[idx + 2] = off + i1;
    if (idx + 2 < N) row_ptr[idx + 3] = off + i2;
    if (idx + 3 < N) row_ptr[idx + 4] = off + i3;
    if (b == 0 && tid == 0) row_ptr[0] = 0;
}

__global__ __launch_bounds__(256) void fill_kernel(
    const int* __restrict__ row, const int* __restrict__ col,
    const float* __restrict__ values, const float* __restrict__ out_norm,
    const int* __restrict__ row_ptr, int* __restrict__ cursor,
    u64* __restrict__ pairs, int E)
{
    int i = blockIdx.x * blockDim.x + threadIdx.x;
    int stride = gridDim.x * blockDim.x;
    for (; i < E; i += stride) {
        int r = row[i], c = col[i];
        float v = values[i] * out_norm[c];
        int pos = row_ptr[r] + atomicAdd(&cursor[r], 1);
        pairs[pos] = (u64)(unsigned)c | ((u64)__float_as_uint(v) << 32);
    }
}

__global__ __launch_bounds__(256) void gather_bf16_kernel(
    const unsigned short* __restrict__ xh, const u64* __restrict__ pairs,
    const int* __restrict__ row_ptr, const float* __restrict__ in_norm,
    float* __restrict__ out, int N, int DU2)
{
    int wid = threadIdx.x >> 6;
    int lane = threadIdx.x & 63;
    int r = blockIdx.x * 4 + wid;
    if (r >= N) return;

    int beg = row_ptr[r], end = row_ptr[r + 1];
    float4 acc = make_float4(0.f, 0.f, 0.f, 0.f);
    const uint2* xr = reinterpret_cast<const uint2*>(xh);

    for (int base = beg; base < end; base += 64) {
        int j = base + lane;
        u64 pr = (j < end) ? pairs[j] : 0ull;
        unsigned prlo = (unsigned)(pr & 0xFFFFFFFFu);
        unsigned prhi = (unsigned)(pr >> 32);
        int m = min(64, end - base);
        int kk = 0;
        for (; kk + 8 <= m; kk += 8) {
            uint2 q[8]; float vv[8];
            #pragma unroll
            for (int t = 0; t < 8; ++t) {
                int c = __builtin_amdgcn_readlane((int)prlo, kk + t);
                unsigned vb = (unsigned)__builtin_amdgcn_readlane((int)prhi, kk + t);
                vv[t] = __uint_as_float(vb);
                q[t] = xr[(size_t)(unsigned)c * DU2 + lane];
            }
            #pragma unroll
            for (int t = 0; t < 8; ++t) {
                acc.x += vv[t] * bf_lo(q[t].x);
                acc.y += vv[t] * bf_hi(q[t].x);
                acc.z += vv[t] * bf_lo(q[t].y);
                acc.w += vv[t] * bf_hi(q[t].y);
            }
        }
        for (; kk < m; ++kk) {
            int c = __builtin_amdgcn_readlane((int)prlo, kk);
            unsigned vb = (unsigned)__builtin_amdgcn_readlane((int)prhi, kk);
            float v = __uint_as_float(vb);
            uint2 q = xr[(size_t)(unsigned)c * DU2 + lane];
            acc.x += v * bf_lo(q.x);
            acc.y += v * bf_hi(q.x);
            acc.z += v * bf_lo(q.y);
            acc.w += v * bf_hi(q.y);
        }
    }

    float sc = in_norm[r];
    f32x4 o;
    o.x = acc.x * sc; o.y = acc.y * sc; o.z = acc.z * sc; o.w = acc.w * sc;
    f32x4* ob = reinterpret_cast<f32x4*>(out);
    __builtin_nontemporal_store(o, &ob[(size_t)r * DU2 + lane]);
}

__global__ __launch_bounds__(256) void gather_kernel(
    const float* __restrict__ x, const u64* __restrict__ pairs,
    const int* __restrict__ row_ptr, const float* __restrict__ in_norm,
    float* __restrict__ out, int N, int D)
{
    int wid = threadIdx.x >> 6;
    int lane = threadIdx.x & 63;
    int r = blockIdx.x * 4 + wid;
    if (r >= N) return;

    int beg = row_ptr[r], end = row_ptr[r + 1];
    float4 acc = make_float4(0.f, 0.f, 0.f, 0.f);
    const float4* xb = reinterpret_cast<const float4*>(x);

    for (int j = beg; j < end; ++j) {
        u64 p = pairs[j];
        int c = (int)(unsigned)(p & 0xFFFFFFFFu);
        float v = __uint_as_float((unsigned)(p >> 32));
        float4 xv = xb[(size_t)c * (D / 4) + lane];
        acc.x += v * xv.x;
        acc.y += v * xv.y;
        acc.z += v * xv.z;
        acc.w += v * xv.w;
    }

    float sc = in_norm[r];
    float4* ob = reinterpret_cast<float4*>(out);
    float4 o;
    o.x = acc.x * sc; o.y = acc.y * sc; o.z = acc.z * sc; o.w = acc.w * sc;
    ob[(size_t)r * (D / 4) + lane] = o;
}

extern "C" void kernel_launch(void* const* d_in, const int* in_sizes, int n_in,
                              void* d_out, int out_size, void* d_ws, size_t ws_size,
                              hipStream_t stream) {
    const float* x        = (const float*)d_in[0];
    const int*   row      = (const int*)  d_in[1];
    const int*   col      = (const int*)  d_in[2];
    const float* values   = (const float*)d_in[3];
    const float* out_norm = (const float*)d_in[4];
    const float* in_norm  = (const float*)d_in[5];
    float* out = (float*)d_out;

    const int E = in_sizes[1];
    const int N = in_sizes[4];
    const int D = in_sizes[0] / N;   // 256

    // ---------- v3: bin + fused LDS path ----------
    {
        const int nbins = (N + 63) >> BIN_LOG2;
        size_t off = 0;
        size_t cnt_off = off;                 off += (size_t)nbins * 4;
        size_t boff_off = off;                off += (size_t)(nbins + 1) * 4;
        size_t bcur_off = off;                off += (size_t)nbins * 4;
        off = (off + 15) & ~(size_t)15;
        size_t pairs_off = off;               off += (size_t)E * 8;
        off = (off + 15) & ~(size_t)15;
        size_t xh_off = off;                  off += (size_t)N * D * 2;
        size_t need = off;

        if (D == 256 && N <= (1 << 18) && nbins <= MAX_BINS && ws_size >= need) {
            int* bin_cnt = (int*)((char*)d_ws + cnt_off);
            int* bin_off = (int*)((char*)d_ws + boff_off);
            int* bin_cur = (int*)((char*)d_ws + bcur_off);
            u64* pairs   = (u64*)((char*)d_ws + pairs_off);
            unsigned short* xh = (unsigned short*)((char*)d_ws + xh_off);

            (void)hipMemsetAsync(bin_cnt, 0, (size_t)nbins * 4, stream);
            int n8 = (N * D) / 8;
            convert_bf16_kernel<<<2048, 256, 0, stream>>>(
                (const u32x4*)x, (u32x4*)xh, n8);
            hist_bins_kernel<<<256, 256, 0, stream>>>(row, bin_cnt, E, nbins);
            scan_bins_kernel<<<1, 64, 0, stream>>>(bin_cnt, bin_off, bin_cur, nbins);
            binfill_kernel<<<2048, 256, 0, stream>>>(
                row, col, values, out_norm, bin_cur, pairs, E);
            fused_bin_gather_kernel<<<nbins, 512, 0, stream>>>(
                xh, pairs, bin_off, in_norm, out, N);
            return;
        }
    }

    // ---------- bucket path (R6) ----------
    {
        size_t off = 0;
        size_t cursor_off = off;              off += (size_t)N * 4;
        size_t ovfc_off   = off;              off += 16;
        size_t ovfr_off   = off;              off += (size_t)OVF_CAP * 4;
        off = (off + 15) & ~(size_t)15;
        size_t ovfcv_off  = off;              off += (size_t)OVF_CAP * 8;
        off = (off + 15) & ~(size_t)15;
        size_t pairs_off  = off;              off += ((size_t)N << BUCKET_LOG2) * 8;
        off = (off + 15) & ~(size_t)15;
        size_t xh_off     = off;              off += (size_t)N * D * 2;
        size_t need_bucket = off;

        if (D == 256 && ws_size >= need_bucket) {
            int* cursor  = (int*)((char*)d_ws + cursor_off);
            int* ovf_cnt = (int*)((char*)d_ws + ovfc_off);
            int* ovf_r   = (int*)((char*)d_ws + ovfr_off);
            u64* ovf_cv  = (u64*)((char*)d_ws + ovfcv_off);
            u64* pairs   = (u64*)((char*)d_ws + pairs_off);
            unsigned short* xh = (unsigned short*)((char*)d_ws + xh_off);

            (void)hipMemsetAsync(cursor, 0, (size_t)N * 4 + 16, stream);
            int n8 = (N * D) / 8;
            convert_bf16_kernel<<<2048, 256, 0, stream>>>(
                (const u32x4*)x, (u32x4*)xh, n8);
            fill_bucket_kernel<<<2048, 256, 0, stream>>>(
                row, col, values, out_norm, cursor, pairs,
                ovf_cnt, ovf_r, ovf_cv, E);
            gather_bucket_kernel<<<(N + 3) / 4, 256, 0, stream>>>(
                xh, pairs, cursor, in_norm, out, N);
            fixup_kernel<<<8, 256, 0, stream>>>(
                xh, ovf_cnt, ovf_r, ovf_cv, in_norm, out);
            return;
        }
    }

    // ---------- exact CSR fallback ----------
    const int nb = (N + 1023) / 1024;
    size_t hdr_ints = (size_t)N + N + (N + 1) + nb;
    hdr_ints = (hdr_ints + 3) & ~(size_t)3;
    size_t pairs_end = hdr_ints * 4 + (size_t)E * 8;
    size_t xh_off = (pairs_end + 15) & ~(size_t)15;
    size_t need_f32  = pairs_end;
    size_t need_bf16 = xh_off + (size_t)N * D * 2;

    if (ws_size < need_f32 || (D % 8) != 0) {
        int n4 = (N * D) / 4;
        zero_out_kernel<<<2048, 256, 0, stream>>>((float4*)out, n4);
        int blocks = (E + 3) / 4;
        edge_scatter_kernel<<<blocks, 256, 0, stream>>>(
            x, row, col, values, out_norm, in_norm, out, E, D);
        return;
    }

    int* counts   = (int*)d_ws;
    int* cursor   = counts + N;
    int* row_ptr  = cursor + N;
    int* partials = row_ptr + N + 1;
    u64* pairs    = (u64*)((int*)d_ws + hdr_ints);
    unsigned short* xh = (unsigned short*)((char*)d_ws + xh_off);

    const bool use_bf16 = (ws_size >= need_bf16);

    (void)hipMemsetAsync(counts, 0, (size_t)2 * N * 4, stream);
    if (use_bf16) {
        int n8 = (N * D) / 8;
        convert_bf16_kernel<<<2048, 256, 0, stream>>>(
            (const u32x4*)x, (u32x4*)xh, n8);
    }
    hist_kernel<<<2048, 256, 0, stream>>>(row, counts, E);
    block_sum_kernel<<<nb, 256, 0, stream>>>(counts, partials, N);
    scan_partials_kernel<<<1, 64, 0, stream>>>(partials, nb);
    scan_block_kernel<<<nb, 256, 0, stream>>>(counts, partials, row_ptr, N);
    fill_kernel<<<2048, 256, 0, stream>>>(row, col, values, out_norm,
                                          row_ptr, cursor, pairs, E);
    if (use_bf16) {
        gather_bf16_kernel<<<(N + 3) / 4, 256, 0, stream>>>(
            xh, pairs, row_ptr, in_norm, out, N, D / 4);
    } else {
        gather_kernel<<<(N + 3) / 4, 256, 0, stream>>>(
            x, pairs, row_ptr, in_norm, out, N, D);
    }
}

// Round 8
// 534.461 us; speedup vs baseline: 9.7215x; 9.7215x over previous
//
#include <hip/hip_runtime.h>

// SpMM: out[r,:] = in_norm[r] * sum_{e: row[e]==r} (values[e]*out_norm[col[e]]) * x[col[e],:]
// Fast path (D==256): fixed-capacity bucket sort (C=64) with out_norm folded
// into bf16-compressed x; convert+fill fused in one dispatch; 16-deep gather.
// Fallbacks: exact CSR (bf16/f32), then atomic scatter.

typedef float f32x4 __attribute__((ext_vector_type(4)));
typedef unsigned int u32x4 __attribute__((ext_vector_type(4)));
typedef unsigned long long u64;

#define BUCKET_LOG2 6
#define BUCKET_CAP  64
#define OVF_CAP     8192
#define CONV_BLKS   768
#define FILL_BLKS   2304

// ---------------- bf16 helpers ----------------
__device__ inline unsigned pack_bf16x2(float lo, float hi) {
    unsigned ua = __float_as_uint(lo);
    unsigned ub = __float_as_uint(hi);
    ua = (ua + 0x7FFFu + ((ua >> 16) & 1u)) >> 16;        // RNE
    ub = (ub + 0x7FFFu + ((ub >> 16) & 1u)) >> 16;
    return ua | (ub << 16);
}
__device__ inline float bf_lo(unsigned u) { return __uint_as_float(u << 16); }
__device__ inline float bf_hi(unsigned u) { return __uint_as_float(u & 0xFFFF0000u); }

// ---------------- fallback (atomic scatter) ----------------
__global__ void zero_out_kernel(float4* out, int n4) {
    int i = blockIdx.x * blockDim.x + threadIdx.x;
    int stride = gridDim.x * blockDim.x;
    for (; i < n4; i += stride) out[i] = make_float4(0.f, 0.f, 0.f, 0.f);
}

__global__ __launch_bounds__(256) void edge_scatter_kernel(
    const float* __restrict__ x, const int* __restrict__ row,
    const int* __restrict__ col, const float* __restrict__ values,
    const float* __restrict__ out_norm, const float* __restrict__ in_norm,
    float* __restrict__ out, int E, int D)
{
    int wave_in_block = threadIdx.x >> 6;
    int lane = threadIdx.x & 63;
    int e = blockIdx.x * 4 + wave_in_block;
    if (e >= E) return;
    int r = row[e], c = col[e];
    float s = values[e] * out_norm[c] * in_norm[r];
    const float4* xs = reinterpret_cast<const float4*>(x + (size_t)c * D);
    float4 v = xs[lane];
    float* o = out + (size_t)r * D + lane * 4;
    atomicAdd(o + 0, v.x * s);
    atomicAdd(o + 1, v.y * s);
    atomicAdd(o + 2, v.z * s);
    atomicAdd(o + 3, v.w * s);
}

// ---------------- fused convert (out_norm folded) + bucket fill -------------
// blocks [0, CONV_BLKS):      xh[c,:] = bf16(out_norm[c] * x[c,:])   (D==256)
// blocks [CONV_BLKS, total):  bucket scatter of (col, values[e])
__global__ __launch_bounds__(256) void convert_fill_kernel(
    const u32x4* __restrict__ x, u32x4* __restrict__ xh,
    const float* __restrict__ out_norm, int n8,
    const int* __restrict__ row, const int* __restrict__ col,
    const float* __restrict__ values,
    int* __restrict__ cursor, u64* __restrict__ pairs,
    int* __restrict__ ovf_cnt, int* __restrict__ ovf_r, u64* __restrict__ ovf_cv,
    int E)
{
    if (blockIdx.x < CONV_BLKS) {
        int i = blockIdx.x * 256 + threadIdx.x;
        const int stride = CONV_BLKS * 256;
        for (; i < n8; i += stride) {
            float s = out_norm[i >> 5];          // D==256: 32 groups of 8 per row
            u32x4 a = __builtin_nontemporal_load(&x[2 * i]);
            u32x4 b = __builtin_nontemporal_load(&x[2 * i + 1]);
            u32x4 o;
            o.x = pack_bf16x2(s * __uint_as_float(a.x), s * __uint_as_float(a.y));
            o.y = pack_bf16x2(s * __uint_as_float(a.z), s * __uint_as_float(a.w));
            o.z = pack_bf16x2(s * __uint_as_float(b.x), s * __uint_as_float(b.y));
            o.w = pack_bf16x2(s * __uint_as_float(b.z), s * __uint_as_float(b.w));
            xh[i] = o;
        }
    } else {
        int i = (blockIdx.x - CONV_BLKS) * 256 + threadIdx.x;
        const int stride = FILL_BLKS * 256;
        for (; i < E; i += stride) {
            int r = __builtin_nontemporal_load(&row[i]);
            int c = __builtin_nontemporal_load(&col[i]);
            float v = __builtin_nontemporal_load(&values[i]);
            u64 packed = (u64)(unsigned)c | ((u64)__float_as_uint(v) << 32);
            int n = atomicAdd(&cursor[r], 1);
            if (n < BUCKET_CAP) {
                pairs[((size_t)r << BUCKET_LOG2) + n] = packed;
            } else {
                int o = atomicAdd(ovf_cnt, 1);
                if (o < OVF_CAP) { ovf_r[o] = r; ovf_cv[o] = packed; }
            }
        }
    }
}

// ---------------- bucket gather: 16-deep, zero-padded batches ----------------
__global__ __launch_bounds__(256) void gather_bucket_kernel(
    const unsigned short* __restrict__ xh, const u64* __restrict__ pairs,
    const int* __restrict__ cursor, const float* __restrict__ in_norm,
    float* __restrict__ out, int N)
{
    const int DU2 = 64;                       // uint2 (4 bf16) per row, D=256
    int wid = threadIdx.x >> 6;
    int lane = threadIdx.x & 63;
    int r = blockIdx.x * 4 + wid;
    if (r >= N) return;

    int m = cursor[r];
    if (m > BUCKET_CAP) m = BUCKET_CAP;

    // one coalesced 512B chunk: this row's whole bucket (invalid lanes -> 0)
    u64 pr = (lane < m)
        ? __builtin_nontemporal_load(&pairs[((size_t)r << BUCKET_LOG2) + lane])
        : 0ull;
    unsigned prlo = (unsigned)(pr & 0xFFFFFFFFu);
    unsigned prhi = (unsigned)(pr >> 32);

    float4 acc = make_float4(0.f, 0.f, 0.f, 0.f);
    const uint2* xr = reinterpret_cast<const uint2*>(xh);

    // zero-padded 16-deep batches: lanes >= m contribute v=0 (c=0 loads are L1-hot)
    for (int kk = 0; kk < m; kk += 16) {
        uint2 q[16];
        float vv[16];
        #pragma unroll
        for (int t = 0; t < 16; ++t) {
            int c = __builtin_amdgcn_readlane((int)prlo, kk + t);
            unsigned vb = (unsigned)__builtin_amdgcn_readlane((int)prhi, kk + t);
            vv[t] = __uint_as_float(vb);
            q[t] = xr[(size_t)(unsigned)c * DU2 + lane];   // 16 independent loads
        }
        #pragma unroll
        for (int t = 0; t < 16; ++t) {
            acc.x += vv[t] * bf_lo(q[t].x);
            acc.y += vv[t] * bf_hi(q[t].x);
            acc.z += vv[t] * bf_lo(q[t].y);
            acc.w += vv[t] * bf_hi(q[t].y);
        }
    }

    float sc = in_norm[r];
    f32x4 o;
    o.x = acc.x * sc; o.y = acc.y * sc; o.z = acc.z * sc; o.w = acc.w * sc;
    f32x4* ob = reinterpret_cast<f32x4*>(out);
    __builtin_nontemporal_store(o, &ob[(size_t)r * DU2 + lane]);
}

// ---------------- overflow fixup (normally 0 entries) ----------------
__global__ __launch_bounds__(256) void fixup_kernel(
    const unsigned short* __restrict__ xh, const int* __restrict__ ovf_cnt,
    const int* __restrict__ ovf_r, const u64* __restrict__ ovf_cv,
    const float* __restrict__ in_norm, float* __restrict__ out)
{
    const int DU2 = 64;
    int total = *ovf_cnt;
    if (total > OVF_CAP) total = OVF_CAP;
    int wid = (blockIdx.x * blockDim.x + threadIdx.x) >> 6;
    int nw = (gridDim.x * blockDim.x) >> 6;
    int lane = threadIdx.x & 63;
    const uint2* xr = reinterpret_cast<const uint2*>(xh);
    for (int i = wid; i < total; i += nw) {
        int r = ovf_r[i];
        u64 p = ovf_cv[i];
        int c = (int)(unsigned)(p & 0xFFFFFFFFu);
        float v = __uint_as_float((unsigned)(p >> 32)) * in_norm[r];
        uint2 q = xr[(size_t)(unsigned)c * DU2 + lane];
        float* o = out + (size_t)r * 256 + lane * 4;
        atomicAdd(o + 0, v * bf_lo(q.x));
        atomicAdd(o + 1, v * bf_hi(q.x));
        atomicAdd(o + 2, v * bf_lo(q.y));
        atomicAdd(o + 3, v * bf_hi(q.y));
    }
}

// ================= exact CSR path (fallback, generic D) =================
__global__ __launch_bounds__(256) void convert_bf16_kernel(
    const u32x4* __restrict__ x, u32x4* __restrict__ xh,
    const float* __restrict__ out_norm, int n8, int d8 /* D/8 */)
{
    int i = blockIdx.x * blockDim.x + threadIdx.x;
    int stride = gridDim.x * blockDim.x;
    for (; i < n8; i += stride) {
        float s = out_norm[i / d8];
        u32x4 a = __builtin_nontemporal_load(&x[2 * i]);
        u32x4 b = __builtin_nontemporal_load(&x[2 * i + 1]);
        u32x4 o;
        o.x = pack_bf16x2(s * __uint_as_float(a.x), s * __uint_as_float(a.y));
        o.y = pack_bf16x2(s * __uint_as_float(a.z), s * __uint_as_float(a.w));
        o.z = pack_bf16x2(s * __uint_as_float(b.x), s * __uint_as_float(b.y));
        o.w = pack_bf16x2(s * __uint_as_float(b.z), s * __uint_as_float(b.w));
        xh[i] = o;
    }
}

__global__ __launch_bounds__(256) void hist_kernel(
    const int* __restrict__ row, int* __restrict__ counts, int E)
{
    int i = blockIdx.x * blockDim.x + threadIdx.x;
    int stride = gridDim.x * blockDim.x;
    for (; i < E; i += stride) atomicAdd(&counts[row[i]], 1);
}

__global__ __launch_bounds__(256) void block_sum_kernel(
    const int* __restrict__ counts, int* __restrict__ partials, int N)
{
    int base = blockIdx.x * 1024;
    int tid = threadIdx.x;
    int s = 0;
    int idx = base + tid * 4;
    #pragma unroll
    for (int k = 0; k < 4; ++k) { int i = idx + k; if (i < N) s += counts[i]; }
    #pragma unroll
    for (int d = 32; d >= 1; d >>= 1) s += __shfl_down(s, d);
    __shared__ int wsum[4];
    int lane = tid & 63, wid = tid >> 6;
    if (lane == 0) wsum[wid] = s;
    __syncthreads();
    if (tid == 0) partials[blockIdx.x] = wsum[0] + wsum[1] + wsum[2] + wsum[3];
}

__global__ void scan_partials_kernel(int* partials, int nb) {
    if (blockIdx.x == 0 && threadIdx.x == 0) {
        int sum = 0;
        for (int b = 0; b < nb; ++b) { int t = partials[b]; partials[b] = sum; sum += t; }
    }
}

__global__ __launch_bounds__(256) void scan_block_kernel(
    const int* __restrict__ counts, const int* __restrict__ partials,
    int* __restrict__ row_ptr, int N)
{
    int b = blockIdx.x;
    int base = b * 1024;
    int tid = threadIdx.x;
    int lane = tid & 63, wid = tid >> 6;
    int idx = base + tid * 4;

    int c0 = (idx + 0 < N) ? counts[idx + 0] : 0;
    int c1 = (idx + 1 < N) ? counts[idx + 1] : 0;
    int c2 = (idx + 2 < N) ? counts[idx + 2] : 0;
    int c3 = (idx + 3 < N) ? counts[idx + 3] : 0;
    int i0 = c0, i1 = i0 + c1, i2 = i1 + c2, i3 = i2 + c3;

    int s = i3;
    #pragma unroll
    for (int d = 1; d < 64; d <<= 1) {
        int t = __shfl_up(s, d);
        if (lane >= d) s += t;
    }
    int excl = s - i3;

    __shared__ int wsum[4];
    if (lane == 63) wsum[wid] = s;
    __syncthreads();
    int woff = 0;
    for (int w = 0; w < wid; ++w) woff += wsum[w];

    int off = partials[b] + woff + excl;
    if (idx + 0 < N) row_ptr[idx + 1] = off + i0;
    if (idx + 1 < N) row_ptr[idx + 2] = off + i1;
    if (idx + 2 < N) row_ptr[idx + 3] = off + i2;
    if (idx + 3 < N) row_ptr[idx + 4] = off + i3;
    if (b == 0 && tid == 0) row_ptr[0] = 0;
}

// mul_norm=1: scale value by out_norm[c] (f32-x path); 0: raw (xh has it folded)
__global__ __launch_bounds__(256) void fill_kernel(
    const int* __restrict__ row, const int* __restrict__ col,
    const float* __restrict__ values, const float* __restrict__ out_norm,
    const int* __restrict__ row_ptr, int* __restrict__ cursor,
    u64* __restrict__ pairs, int E, int mul_norm)
{
    int i = blockIdx.x * blockDim.x + threadIdx.x;
    int stride = gridDim.x * blockDim.x;
    for (; i < E; i += stride) {
        int r = row[i], c = col[i];
        float v = values[i];
        if (mul_norm) v *= out_norm[c];
        int pos = row_ptr[r] + atomicAdd(&cursor[r], 1);
        pairs[pos] = (u64)(unsigned)c | ((u64)__float_as_uint(v) << 32);
    }
}

__global__ __launch_bounds__(256) void gather_bf16_kernel(
    const unsigned short* __restrict__ xh, const u64* __restrict__ pairs,
    const int* __restrict__ row_ptr, const float* __restrict__ in_norm,
    float* __restrict__ out, int N, int DU2)
{
    int wid = threadIdx.x >> 6;
    int lane = threadIdx.x & 63;
    int r = blockIdx.x * 4 + wid;
    if (r >= N) return;

    int beg = row_ptr[r], end = row_ptr[r + 1];
    float4 acc = make_float4(0.f, 0.f, 0.f, 0.f);
    const uint2* xr = reinterpret_cast<const uint2*>(xh);

    for (int base = beg; base < end; base += 64) {
        int j = base + lane;
        u64 pr = (j < end) ? pairs[j] : 0ull;
        unsigned prlo = (unsigned)(pr & 0xFFFFFFFFu);
        unsigned prhi = (unsigned)(pr >> 32);
        int m = min(64, end - base);
        for (int kk = 0; kk < m; kk += 8) {
            uint2 q[8]; float vv[8];
            #pragma unroll
            for (int t = 0; t < 8; ++t) {
                int c = __builtin_amdgcn_readlane((int)prlo, kk + t);
                unsigned vb = (unsigned)__builtin_amdgcn_readlane((int)prhi, kk + t);
                vv[t] = __uint_as_float(vb);
                q[t] = xr[(size_t)(unsigned)c * DU2 + lane];
            }
            #pragma unroll
            for (int t = 0; t < 8; ++t) {
                acc.x += vv[t] * bf_lo(q[t].x);
                acc.y += vv[t] * bf_hi(q[t].x);
                acc.z += vv[t] * bf_lo(q[t].y);
                acc.w += vv[t] * bf_hi(q[t].y);
            }
        }
    }

    float sc = in_norm[r];
    f32x4 o;
    o.x = acc.x * sc; o.y = acc.y * sc; o.z = acc.z * sc; o.w = acc.w * sc;
    f32x4* ob = reinterpret_cast<f32x4*>(out);
    __builtin_nontemporal_store(o, &ob[(size_t)r * DU2 + lane]);
}

__global__ __launch_bounds__(256) void gather_kernel(
    const float* __restrict__ x, const u64* __restrict__ pairs,
    const int* __restrict__ row_ptr, const float* __restrict__ in_norm,
    float* __restrict__ out, int N, int D)
{
    int wid = threadIdx.x >> 6;
    int lane = threadIdx.x & 63;
    int r = blockIdx.x * 4 + wid;
    if (r >= N) return;

    int beg = row_ptr[r], end = row_ptr[r + 1];
    float4 acc = make_float4(0.f, 0.f, 0.f, 0.f);
    const float4* xb = reinterpret_cast<const float4*>(x);

    for (int j = beg; j < end; ++j) {
        u64 p = pairs[j];
        int c = (int)(unsigned)(p & 0xFFFFFFFFu);
        float v = __uint_as_float((unsigned)(p >> 32));
        float4 xv = xb[(size_t)c * (D / 4) + lane];
        acc.x += v * xv.x;
        acc.y += v * xv.y;
        acc.z += v * xv.z;
        acc.w += v * xv.w;
    }

    float sc = in_norm[r];
    float4* ob = reinterpret_cast<float4*>(out);
    float4 o;
    o.x = acc.x * sc; o.y = acc.y * sc; o.z = acc.z * sc; o.w = acc.w * sc;
    ob[(size_t)r * (D / 4) + lane] = o;
}

extern "C" void kernel_launch(void* const* d_in, const int* in_sizes, int n_in,
                              void* d_out, int out_size, void* d_ws, size_t ws_size,
                              hipStream_t stream) {
    const float* x        = (const float*)d_in[0];
    const int*   row      = (const int*)  d_in[1];
    const int*   col      = (const int*)  d_in[2];
    const float* values   = (const float*)d_in[3];
    const float* out_norm = (const float*)d_in[4];
    const float* in_norm  = (const float*)d_in[5];
    float* out = (float*)d_out;

    const int E = in_sizes[1];
    const int N = in_sizes[4];
    const int D = in_sizes[0] / N;   // 256

    // ---------- fast bucket path (D==256) ----------
    {
        size_t off = 0;
        size_t cursor_off = off;              off += (size_t)N * 4;
        size_t ovfc_off   = off;              off += 16;
        size_t ovfr_off   = off;              off += (size_t)OVF_CAP * 4;
        off = (off + 15) & ~(size_t)15;
        size_t ovfcv_off  = off;              off += (size_t)OVF_CAP * 8;
        off = (off + 15) & ~(size_t)15;
        size_t pairs_off  = off;              off += ((size_t)N << BUCKET_LOG2) * 8;
        off = (off + 15) & ~(size_t)15;
        size_t xh_off     = off;              off += (size_t)N * D * 2;
        size_t need_bucket = off;

        if (D == 256 && ws_size >= need_bucket) {
            int* cursor  = (int*)((char*)d_ws + cursor_off);
            int* ovf_cnt = (int*)((char*)d_ws + ovfc_off);
            int* ovf_r   = (int*)((char*)d_ws + ovfr_off);
            u64* ovf_cv  = (u64*)((char*)d_ws + ovfcv_off);
            u64* pairs   = (u64*)((char*)d_ws + pairs_off);
            unsigned short* xh = (unsigned short*)((char*)d_ws + xh_off);

            (void)hipMemsetAsync(cursor, 0, (size_t)N * 4 + 16, stream);
            int n8 = (N * D) / 8;
            convert_fill_kernel<<<CONV_BLKS + FILL_BLKS, 256, 0, stream>>>(
                (const u32x4*)x, (u32x4*)xh, out_norm, n8,
                row, col, values, cursor, pairs, ovf_cnt, ovf_r, ovf_cv, E);
            gather_bucket_kernel<<<(N + 3) / 4, 256, 0, stream>>>(
                xh, pairs, cursor, in_norm, out, N);
            fixup_kernel<<<8, 256, 0, stream>>>(
                xh, ovf_cnt, ovf_r, ovf_cv, in_norm, out);
            return;
        }
    }

    // ---------- exact CSR fallback ----------
    const int nb = (N + 1023) / 1024;
    size_t hdr_ints = (size_t)N + N + (N + 1) + nb;
    hdr_ints = (hdr_ints + 3) & ~(size_t)3;
    size_t pairs_end = hdr_ints * 4 + (size_t)E * 8;
    size_t xh_off = (pairs_end + 15) & ~(size_t)15;
    size_t need_f32  = pairs_end;
    size_t need_bf16 = xh_off + (size_t)N * D * 2;

    if (ws_size < need_f32 || (D % 8) != 0) {
        int n4 = (N * D) / 4;
        zero_out_kernel<<<2048, 256, 0, stream>>>((float4*)out, n4);
        int blocks = (E + 3) / 4;
        edge_scatter_kernel<<<blocks, 256, 0, stream>>>(
            x, row, col, values, out_norm, in_norm, out, E, D);
        return;
    }

    int* counts   = (int*)d_ws;
    int* cursor   = counts + N;
    int* row_ptr  = cursor + N;
    int* partials = row_ptr + N + 1;
    u64* pairs    = (u64*)((int*)d_ws + hdr_ints);
    unsigned short* xh = (unsigned short*)((char*)d_ws + xh_off);

    const bool use_bf16 = (ws_size >= need_bf16);

    (void)hipMemsetAsync(counts, 0, (size_t)2 * N * 4, stream);
    if (use_bf16) {
        int n8 = (N * D) / 8;
        convert_bf16_kernel<<<2048, 256, 0, stream>>>(
            (const u32x4*)x, (u32x4*)xh, out_norm, n8, D / 8);
    }
    hist_kernel<<<2048, 256, 0, stream>>>(row, counts, E);
    block_sum_kernel<<<nb, 256, 0, stream>>>(counts, partials, N);
    scan_partials_kernel<<<1, 64, 0, stream>>>(partials, nb);
    scan_block_kernel<<<nb, 256, 0, stream>>>(counts, partials, row_ptr, N);
    fill_kernel<<<2048, 256, 0, stream>>>(row, col, values, out_norm,
                                          row_ptr, cursor, pairs, E,
                                          use_bf16 ? 0 : 1);
    if (use_bf16) {
        gather_bf16_kernel<<<(N + 3) / 4, 256, 0, stream>>>(
            xh, pairs, row_ptr, in_norm, out, N, D / 4);
    } else {
        gather_kernel<<<(N + 3) / 4, 256, 0, stream>>>(
            x, pairs, row_ptr, in_norm, out, N, D);
    }
}